// Round 1
// baseline (359.640 us; speedup 1.0000x reference)
//
#include <hip/hip_runtime.h>
#include <hip/hip_fp16.h>
#include <cmath>

#define EPS 1e-5f
#define TAU 0.15f
#define RP  8

// Problem constants (fixed instance)
#define Bn 16
#define Dn 256
#define Tn 4096
#define Kn 2048
#define NSLOT 16   // 8 ks-blocks x 2 wn-halves

typedef unsigned short ushort_t;
typedef __attribute__((ext_vector_type(8))) _Float16 f16x8;
typedef __attribute__((ext_vector_type(4))) float f32x4;

__device__ __forceinline__ unsigned short f2h(float v) {
    return __half_as_ushort(__float2half_rn(v));
}

// fp16 rounded UP in value (result >= v). ulp <= 0.125 for |v| < 256.
__device__ __forceinline__ unsigned short f16_up(float v) {
    const __half h = __float2half_rn(v);
    const float back = __half2float(h);
    unsigned short u = __half_as_ushort(h);
    if (back < v) u = (u & 0x8000u) ? (u - 1) : (u + 1);
    return u;
}

#define GLOAD_LDS16(gp, lp) __builtin_amdgcn_global_load_lds( \
    (const __attribute__((address_space(1))) unsigned int*)(gp), \
    (__attribute__((address_space(3))) unsigned int*)(lp), 16, 0, 0)

// ---------------------------------------------------------------------------
// Kernel 1: prep — emb = es/max(usage,eps); e16 fp16 plane; bias = 0.5|e|^2;
// embT4 transpose. (unchanged)
// ---------------------------------------------------------------------------
__global__ __launch_bounds__(256) void prep_kernel(
    const float* __restrict__ es, const float* __restrict__ usage,
    float* __restrict__ emb, ushort_t* __restrict__ e16,
    float* __restrict__ bias, float4* __restrict__ embT4,
    int* __restrict__ counter)
{
    __shared__ float sh[256];
    __shared__ float wsum[4];
    const int k = blockIdx.x;
    const int d = threadIdx.x;
    const float inv = 1.0f / fmaxf(usage[k], EPS);
    const float v = es[(size_t)k * Dn + d] * inv;
    emb[(size_t)k * Dn + d] = v;
    e16[(size_t)k * Dn + d] = f2h(fminf(fmaxf(v, -65504.f), 65504.f));
    sh[d] = v;
    float sq = v * v;
    #pragma unroll
    for (int off = 32; off > 0; off >>= 1) sq += __shfl_down(sq, off, 64);
    const int lane = d & 63, wv = d >> 6;
    if (lane == 0) wsum[wv] = sq;
    __syncthreads();
    if (d < 64)
        embT4[(size_t)d * Kn + k] = make_float4(sh[4*d], sh[4*d+1], sh[4*d+2], sh[4*d+3]);
    if (d == 0) {
        bias[k] = 0.5f * (wsum[0] + wsum[1] + wsum[2] + wsum[3]);
        if (k == 0) *counter = 0;
    }
}

// ---------------------------------------------------------------------------
// Kernel 2: xsplit — x[b][d][t] fp32 -> xh[b][t][d] fp16. (unchanged)
// ---------------------------------------------------------------------------
__global__ __launch_bounds__(256) void xsplit_kernel(
    const float* __restrict__ x, ushort_t* __restrict__ xh)
{
    __shared__ float tile[32 * 65];
    const int t0 = blockIdx.x * 64;
    const int d0 = blockIdx.y * 32;
    const int b  = blockIdx.z;
    const int tid = threadIdx.x;

    {
        const int dl = tid >> 3, tq = tid & 7;
        const float* src = x + ((size_t)(b * Dn + d0 + dl)) * Tn + t0 + tq * 8;
        const float4 a = *(const float4*)(src);
        const float4 c = *(const float4*)(src + 4);
        float* row = &tile[dl * 65 + tq * 8];
        row[0] = a.x; row[1] = a.y; row[2] = a.z; row[3] = a.w;
        row[4] = c.x; row[5] = c.y; row[6] = c.z; row[7] = c.w;
    }
    __syncthreads();
    {
        const int t_l = tid >> 2, dq = tid & 3;
        unsigned wh[4];
        #pragma unroll
        for (int i = 0; i < 4; ++i) {
            const float a = tile[(dq * 8 + 2 * i) * 65 + t_l];
            const float g = tile[(dq * 8 + 2 * i + 1) * 65 + t_l];
            wh[i] = (unsigned)f2h(a) | ((unsigned)f2h(g) << 16);
        }
        const size_t o = ((size_t)(b * Tn + t0 + t_l)) * Dn + d0 + dq * 8;
        *(uint4*)(xh + o) = make_uint4(wh[0], wh[1], wh[2], wh[3]);
    }
}

// ---------------------------------------------------------------------------
// Kernel 3 (REWRITTEN): 256t x 256k block, 8 waves (4M x 2N), BK=64,
// double-buffered 128 KB LDS, counted-vmcnt pipeline (T3+T4), XOR-swizzled
// LDS (T2: linear gload_lds dest + inverse-swizzled SOURCE + swizzled read),
// setprio around MFMA clusters (T5).  Contraction D=256 -> 4 BK-steps.
//
// vmcnt ledger (8 gload_lds per STAGE, per thread):
//   STAGE(b0,d0) STAGE(b1,d64)            -> 16 outstanding
//   vmcnt(8)  : b0 ready    | COMPUTE b0
//   barrier (WAR) STAGE(b0,d128)          -> <=16 outstanding
//   vmcnt(8)  : b1 ready    | COMPUTE b1
//   barrier (WAR) STAGE(b1,d192)
//   vmcnt(8)  : b0 ready    | COMPUTE b0
//   vmcnt(0)  : b1 ready    | COMPUTE b1
// Per-wave output: 64t x 128k; top-2 over k via j-loop + 16-lane butterfly;
// 16 rec slots (ks*2+wn), slots ascend in k for tie-break order.
// ---------------------------------------------------------------------------
#define STAGE(q, d0)                                                          \
    {                                                                         \
        _Pragma("unroll")                                                     \
        for (int r = 0; r < 4; ++r) {                                         \
            const int cb = r * 512 + (wid << 6);                              \
            GLOAD_LDS16(xh + (bTt0 + srow[r]) * Dn + (d0) + scol[r],          \
                        &As[q][cb << 3]);                                     \
        }                                                                     \
        _Pragma("unroll")                                                     \
        for (int r = 0; r < 4; ++r) {                                         \
            const int cb = r * 512 + (wid << 6);                              \
            GLOAD_LDS16(e16 + ((size_t)(kbase + srow[r])) * Dn + (d0) + scol[r], \
                        &Bs[q][cb << 3]);                                     \
        }                                                                     \
    }

#define COMPUTE(q)                                                            \
    {                                                                         \
        _Pragma("unroll")                                                     \
        for (int sub = 0; sub < 2; ++sub) {                                   \
            const int slot8 = ((((sub << 2) | quad) ^ x7) << 3);              \
            f16x8 af[4]; f16x8 bf[8];                                         \
            _Pragma("unroll")                                                 \
            for (int i = 0; i < 4; ++i)                                       \
                af[i] = *(const f16x8*)(&As[q][aoffbase + (i << 10) + slot8]);\
            _Pragma("unroll")                                                 \
            for (int j = 0; j < 8; ++j)                                       \
                bf[j] = *(const f16x8*)(&Bs[q][boffbase + (j << 10) + slot8]);\
            __builtin_amdgcn_s_setprio(1);                                    \
            _Pragma("unroll")                                                 \
            for (int i = 0; i < 4; ++i)                                       \
                _Pragma("unroll")                                             \
                for (int j = 0; j < 8; ++j)                                   \
                    acc[i][j] = __builtin_amdgcn_mfma_f32_16x16x32_f16(       \
                        af[i], bf[j], acc[i][j], 0, 0, 0);                    \
            __builtin_amdgcn_s_setprio(0);                                    \
        }                                                                     \
    }

#define BARRIER_PIN()                                                         \
    __builtin_amdgcn_s_barrier();                                             \
    __builtin_amdgcn_sched_barrier(0)

__global__ __launch_bounds__(512, 2) void gemm_argmax(
    const ushort_t* __restrict__ xh, const ushort_t* __restrict__ e16,
    const float* __restrict__ bias, uint2* __restrict__ rec)
{
    __shared__ __align__(16) ushort_t As[2][256 * 64];   // [t][d64], 2 x 32 KB
    __shared__ __align__(16) ushort_t Bs[2][256 * 64];   // [k][d64], 2 x 32 KB

    const int bid   = blockIdx.x;
    const int xcd   = bid & 7;
    const int ks    = (bid >> 3) & 7;
    const int tilid = bid >> 6;
    const int gtile = tilid * 8 + xcd;   // ks-siblings of one (b,tt) share an XCD
    const int b     = gtile >> 4;
    const int tt    = gtile & 15;
    const int t0    = tt << 8;
    const int kbase = ks << 8;

    const int tid  = threadIdx.x;
    const int lane = tid & 63;
    const int wid  = tid >> 6;
    const int l15  = lane & 15;
    const int quad = lane >> 4;
    const int wm   = wid >> 1;      // 0..3 : t-quarter (64 rows)
    const int wn   = wid & 1;       // 0..1 : k-half (128 cols)
    const int x7   = l15 & 7;

    const size_t bTt0 = (size_t)b * Tn + t0;

    // stage chunks: round r -> chunk c = r*512+tid; row=c>>3, col16=c&7.
    // LDS dest is LINEAR (gload_lds requirement); SOURCE col is inverse-
    // swizzled so a swizzled read recovers linear data (rule #21).
    int srow[4], scol[4];
    #pragma unroll
    for (int r = 0; r < 4; ++r) {
        const int c = r * 512 + tid;
        srow[r] = c >> 3;
        scol[r] = (((c & 7) ^ (srow[r] & 7)) << 3);   // halfword offset
    }

    // fragment read bases (shorts). row&7 == l15&7 for all i/j (strides %8==0)
    const int aoffbase = ((wm << 6) + l15) << 6;       // (wm*64 + l15)*64
    const int boffbase = ((wn << 7) + l15) << 6;       // (wn*128 + l15)*64

    f32x4 acc[4][8];
    #pragma unroll
    for (int i = 0; i < 4; ++i)
        #pragma unroll
        for (int j = 0; j < 8; ++j) acc[i][j] = (f32x4){0.f, 0.f, 0.f, 0.f};

    STAGE(0, 0);
    STAGE(1, 64);
    asm volatile("s_waitcnt vmcnt(8)" ::: "memory");
    BARRIER_PIN();
    COMPUTE(0);                                  // d[0:64)
    BARRIER_PIN();                               // WAR: readers of buf0 done
    STAGE(0, 128);
    asm volatile("s_waitcnt vmcnt(8)" ::: "memory");
    BARRIER_PIN();
    COMPUTE(1);                                  // d[64:128)
    BARRIER_PIN();                               // WAR: readers of buf1 done
    STAGE(1, 192);
    asm volatile("s_waitcnt vmcnt(8)" ::: "memory");
    BARRIER_PIN();
    COMPUTE(0);                                  // d[128:192)
    asm volatile("s_waitcnt vmcnt(0)" ::: "memory");
    BARRIER_PIN();
    COMPUTE(1);                                  // d[192:256)

    // ---- epilogue: bias + top-2 over the wave's 128 k, 16-lane butterfly ----
    __builtin_amdgcn_sched_barrier(0);           // keep bias loads out of the
                                                 // vmcnt-counted region
    const int kw = kbase + (wn << 7);
    float bj[8];
    #pragma unroll
    for (int j = 0; j < 8; ++j) bj[j] = bias[kw + (j << 4) + l15];

    const int slot = (ks << 1) | wn;             // ascending in k
    #pragma unroll
    for (int i = 0; i < 4; ++i) {
        float s1[4], s2[4]; int k1[4];
        #pragma unroll
        for (int r = 0; r < 4; ++r) { s1[r] = -INFINITY; s2[r] = -INFINITY; k1[r] = 0; }
        #pragma unroll
        for (int j = 0; j < 8; ++j) {            // k ascending
            const int kg = kw + (j << 4) + l15;
            #pragma unroll
            for (int r = 0; r < 4; ++r) {
                const float s = acc[i][j][r] - bj[j];
                if (s > s1[r]) { s2[r] = s1[r]; s1[r] = s; k1[r] = kg; }
                else if (s > s2[r]) s2[r] = s;
            }
        }
        #pragma unroll
        for (int m = 1; m <= 8; m <<= 1) {
            #pragma unroll
            for (int r = 0; r < 4; ++r) {
                const float os1 = __shfl_xor(s1[r], m);
                const float os2 = __shfl_xor(s2[r], m);
                const int   ok1 = __shfl_xor(k1[r], m);
                const bool take = (os1 > s1[r]) || (os1 == s1[r] && ok1 < k1[r]);
                const float ns2 = take ? fmaxf(s1[r], os2) : fmaxf(s2[r], os1);
                if (take) { s1[r] = os1; k1[r] = ok1; }
                s2[r] = ns2;
            }
        }
        if (l15 == 0) {
            #pragma unroll
            for (int r = 0; r < 4; ++r) {
                const int row = (wm << 6) + (i << 4) + (quad << 2) + r;
                uint2 e;
                e.x = __float_as_uint(s1[r]);
                e.y = ((unsigned)f16_up(s2[r]) << 16) | (unsigned)k1[r];
                rec[(size_t)slot * (Bn * Tn) + bTt0 + row] = e;
            }
        }
    }
}

// ---------------------------------------------------------------------------
// Kernel 4: merge 16 slot-major records per point; codes + rescue list.
// ---------------------------------------------------------------------------
__global__ __launch_bounds__(256) void merge_kernel(
    const uint2* __restrict__ rec, int* __restrict__ codes_i,
    float* __restrict__ codes_f, int* __restrict__ list, int* __restrict__ counter)
{
    const int p = blockIdx.x * 256 + threadIdx.x;
    uint2 e = rec[p];
    float g1 = __uint_as_float(e.x);
    float g2 = __half2float(__ushort_as_half((unsigned short)(e.y >> 16)));
    int kk = (int)(e.y & 0xffffu);
    #pragma unroll
    for (int s = 1; s < NSLOT; ++s) {             // slots ascending in k
        e = rec[(size_t)s * (Bn * Tn) + p];
        const float s1 = __uint_as_float(e.x);
        if (s1 > g1) {
            const float s2u = __half2float(__ushort_as_half((unsigned short)(e.y >> 16)));
            g2 = fmaxf(fmaxf(g2, g1), s2u);
            g1 = s1;
            kk = (int)(e.y & 0xffffu);
        } else {
            g2 = fmaxf(g2, s1);
        }
    }
    codes_i[p] = kk;
    codes_f[p] = (float)kk;
    if (g1 - g2 < TAU) {
        const int idx = atomicAdd(counter, 1);
        list[idx] = p;
    }
}

// ---------------------------------------------------------------------------
// Kernel 5: exact fp32 rescore (unchanged)
// ---------------------------------------------------------------------------
__global__ __launch_bounds__(256) void rescue_kernel(
    const float* __restrict__ x, const float4* __restrict__ embT4,
    const float* __restrict__ bias, const int* __restrict__ list,
    const int* __restrict__ counter, int* __restrict__ codes_i,
    float* __restrict__ codes_f)
{
    __shared__ float xv[RP][256];
    __shared__ int plist[RP];
    __shared__ float rs[RP][4];
    __shared__ int   rk[RP][4];
    const int tid = threadIdx.x, lane = tid & 63, wid = tid >> 6;
    const int count = *counter;
    for (int base = blockIdx.x * RP; base < count; base += gridDim.x * RP) {
        const int npts = min(RP, count - base);
        __syncthreads();
        if (tid < npts) plist[tid] = list[base + tid];
        __syncthreads();
        for (int pi = 0; pi < npts; ++pi) {
            const int p = plist[pi];
            xv[pi][tid] = x[((size_t)((p >> 12) * Dn + tid)) * Tn + (p & 4095)];
        }
        for (int pi = npts; pi < RP; ++pi) xv[pi][tid] = 0.f;
        __syncthreads();

        float acc[8][RP];
        #pragma unroll
        for (int s = 0; s < 8; ++s)
            #pragma unroll
            for (int pi = 0; pi < RP; ++pi) acc[s][pi] = 0.f;

        for (int dc = 0; dc < 64; ++dc) {
            float4 ev[8];
            #pragma unroll
            for (int s = 0; s < 8; ++s)
                ev[s] = embT4[(size_t)dc * Kn + tid + (s << 8)];
            #pragma unroll
            for (int pi = 0; pi < RP; ++pi) {
                const float4 xw = *(const float4*)&xv[pi][dc << 2];
                #pragma unroll
                for (int s = 0; s < 8; ++s)
                    acc[s][pi] += ev[s].x * xw.x + ev[s].y * xw.y
                                + ev[s].z * xw.z + ev[s].w * xw.w;
            }
        }

        float bs[RP]; int bk[RP];
        #pragma unroll
        for (int pi = 0; pi < RP; ++pi) { bs[pi] = -INFINITY; bk[pi] = 0; }
        #pragma unroll
        for (int s = 0; s < 8; ++s) {
            const int kk = tid + (s << 8);
            const float bv = bias[kk];
            #pragma unroll
            for (int pi = 0; pi < RP; ++pi) {
                const float sc = acc[s][pi] - bv;
                if (sc > bs[pi]) { bs[pi] = sc; bk[pi] = kk; }
            }
        }
        #pragma unroll
        for (int off = 1; off < 64; off <<= 1) {
            #pragma unroll
            for (int pi = 0; pi < RP; ++pi) {
                const float os = __shfl_xor(bs[pi], off);
                const int   ok = __shfl_xor(bk[pi], off);
                if (os > bs[pi] || (os == bs[pi] && ok < bk[pi])) { bs[pi] = os; bk[pi] = ok; }
            }
        }
        if (lane == 0) {
            #pragma unroll
            for (int pi = 0; pi < RP; ++pi) { rs[pi][wid] = bs[pi]; rk[pi][wid] = bk[pi]; }
        }
        __syncthreads();
        if (tid < npts) {
            float fs = rs[tid][0]; int fk = rk[tid][0];
            #pragma unroll
            for (int w = 1; w < 4; ++w) {
                if (rs[tid][w] > fs || (rs[tid][w] == fs && rk[tid][w] < fk)) {
                    fs = rs[tid][w]; fk = rk[tid][w];
                }
            }
            const int p = plist[tid];
            codes_i[p] = fk;
            codes_f[p] = (float)fk;
        }
    }
}

// ---------------------------------------------------------------------------
// Kernel 6: decode (unchanged)
// ---------------------------------------------------------------------------
__global__ __launch_bounds__(256) void decode_kernel(
    const float* __restrict__ emb, const int* __restrict__ codes,
    float* __restrict__ out)
{
    const int b = blockIdx.y;
    const int t = blockIdx.x * 256 + threadIdx.x;
    const int c = codes[(size_t)b * Tn + t];
    const float4* e4 = (const float4*)(emb + (size_t)c * Dn);
    float* ob = out + (size_t)b * Dn * Tn + t;
    #pragma unroll 4
    for (int d4 = 0; d4 < 64; ++d4) {
        const float4 v = e4[d4];
        ob[(size_t)(d4 * 4 + 0) * Tn] = v.x;
        ob[(size_t)(d4 * 4 + 1) * Tn] = v.y;
        ob[(size_t)(d4 * 4 + 2) * Tn] = v.z;
        ob[(size_t)(d4 * 4 + 3) * Tn] = v.w;
    }
}

// ---------------------------------------------------------------------------
extern "C" void kernel_launch(void* const* d_in, const int* in_sizes, int n_in,
                              void* d_out, int out_size, void* d_ws, size_t ws_size,
                              hipStream_t stream) {
    const float* x     = (const float*)d_in[0];   // [B, D, T]
    const float* es    = (const float*)d_in[1];   // [K, D]
    const float* usage = (const float*)d_in[2];   // [K]

    // ws layout (byte offsets, 16-aligned) — ~6 MiB
    char* ws = (char*)d_ws;
    float*    emb     = (float*)(ws + 0);                // 2 MiB
    float*    bias    = (float*)(ws + 2097152);          // 8 KB
    ushort_t* e16     = (ushort_t*)(ws + 2105344);       // 1 MiB
    float4*   embT4   = (float4*)(ws + 3153920);         // 2 MiB
    int*      codes_i = (int*)(ws + 5251072);            // 256 KB
    int*      list    = (int*)(ws + 5513216);            // 256 KB
    int*      counter = (int*)(ws + 5775360);            // 4 B

    float* codes_f = (float*)d_out;                      // [B*T]
    float* decoded = (float*)d_out + (size_t)Bn * Tn;    // [B*D*T], 64 MiB

    // xh (fp16, 32 MiB) and rec (16 slots x 512 KB = 8 MiB) live inside the
    // decoded region; decode overwrites at the very end, after both consumed.
    ushort_t* xh  = (ushort_t*)decoded;                            // 32 MiB
    uint2*    rec = (uint2*)((char*)decoded + 33554432);           // 8 MiB

    prep_kernel<<<Kn, 256, 0, stream>>>(es, usage, emb, e16, bias, embT4, counter);

    dim3 gx(Tn / 64, Dn / 32, Bn);
    xsplit_kernel<<<gx, 256, 0, stream>>>(x, xh);

    // 256 t-tiles (BM=256) x 8 k-splits (BN=256) = 2048 blocks x 512 threads
    gemm_argmax<<<2048, 512, 0, stream>>>(xh, e16, bias, rec);

    merge_kernel<<<(Bn * Tn) / 256, 256, 0, stream>>>(rec, codes_i, codes_f, list, counter);

    rescue_kernel<<<1024, 256, 0, stream>>>(x, embT4, bias, list, counter, codes_i, codes_f);

    dim3 g6(Tn / 256, Bn);
    decode_kernel<<<g6, 256, 0, stream>>>(emb, codes_i, decoded);
}